// Round 19
// baseline (490.337 us; speedup 1.0000x reference)
//
#include <hip/hip_runtime.h>

#define Bb 4
#define Ss 2048
#define Dd 1024
#define Hh 16
#define DFF 4096

typedef unsigned short u16;
typedef __attribute__((ext_vector_type(8))) short v8s;
typedef __attribute__((ext_vector_type(4))) float v4f;
typedef __attribute__((ext_vector_type(4))) unsigned short v4u16;
typedef __attribute__((ext_vector_type(4))) unsigned v4u;

__device__ __forceinline__ u16 f2bf(float f) {
  unsigned u = __builtin_bit_cast(unsigned, f);
  return (u16)((u + 0x7fffu + ((u >> 16) & 1u)) >> 16);   // RNE
}

__device__ __forceinline__ unsigned cvtpk(float a, float b) {
  unsigned r;
  asm("v_cvt_pk_bf16_f32 %0, %1, %2" : "=v"(r) : "v"(a), "v"(b));
  return r;
}

__device__ __forceinline__ void gload16(const void* g, void* l) {
  __builtin_amdgcn_global_load_lds((const __attribute__((address_space(1))) unsigned*)g,
                                   (__attribute__((address_space(3))) unsigned*)l, 16, 0, 0);
}

__device__ __forceinline__ v4f mfma16(v8s a, v8s b, v4f c) {
  return __builtin_amdgcn_mfma_f32_16x16x32_bf16(a, b, c, 0, 0, 0);
}

// Schraudolph fast exp2 (mask pre-folded by caller).
__device__ __forceinline__ float fexp2_raw(float s) {
  const int i = (int)__builtin_fmaf(s, 8388608.0f, 1064998378.0f);
  return __builtin_bit_cast(float, i);
}

__device__ __forceinline__ float gelu_f(float x) {
  float y = 0.7978845608028654f * (x + 0.044715f * x * x * x);
  y = fminf(fmaxf(y, -15.f), 15.f);
  float t = 1.0f - 2.0f / (__expf(2.0f * y) + 1.0f);
  return 0.5f * x * (1.0f + t);
}

// ---------------- LayerNorm (ddof=1, eps on std), fp32 in -> bf16 out -------
__global__ __launch_bounds__(256)
void ln_k(const float* __restrict__ x, const float* __restrict__ ga,
          const float* __restrict__ gb, u16* __restrict__ out) {
  const int row = blockIdx.x, tid = threadIdx.x;
  const float4 v = ((const float4*)(x + (size_t)row * 1024))[tid];
  float s = v.x + v.y + v.z + v.w;
  float q = v.x * v.x + v.y * v.y + v.z * v.z + v.w * v.w;
  #pragma unroll
  for (int o = 1; o < 64; o <<= 1) { s += __shfl_xor(s, o); q += __shfl_xor(q, o); }
  __shared__ float red[8];
  if ((tid & 63) == 0) { red[tid >> 6] = s; red[4 + (tid >> 6)] = q; }
  __syncthreads();
  s = red[0] + red[1] + red[2] + red[3];
  q = red[4] + red[5] + red[6] + red[7];
  const float mean = s * (1.0f / 1024.0f);
  const float var = fmaxf((q - 1024.0f * mean * mean) * (1.0f / 1023.0f), 0.0f);
  const float inv = 1.0f / (sqrtf(var) + 1e-6f);
  const int c0 = tid * 4;
  u16* o4 = out + (size_t)row * 1024 + c0;
  const float vv[4] = {v.x, v.y, v.z, v.w};
  #pragma unroll
  for (int i = 0; i < 4; i++)
    o4[i] = f2bf(ga[c0 + i] * (vv[i] - mean) * inv + gb[c0 + i]);
}

// ---------------- weight transpose: W[K][N] fp32 -> Wt[N][K] bf16 -----------
__global__ __launch_bounds__(256)
void wt_k(const float* __restrict__ w, u16* __restrict__ wt, int K, int N) {
  __shared__ float tile[32 * 33];
  const int t = threadIdx.x;
  const int k0 = blockIdx.x << 5, n0 = blockIdx.y << 5;
  {
    const int r = t >> 3, c4 = (t & 7) << 2;
    const float4 v = *(const float4*)&w[(size_t)(k0 + r) * N + n0 + c4];
    tile[r * 33 + c4 + 0] = v.x; tile[r * 33 + c4 + 1] = v.y;
    tile[r * 33 + c4 + 2] = v.z; tile[r * 33 + c4 + 3] = v.w;
  }
  __syncthreads();
  {
    const int r = t >> 3, c4 = (t & 7) << 2;  // r: n-offset, c4: k-offset
    v4u16 uv;
    #pragma unroll
    for (int i = 0; i < 4; i++) uv[i] = f2bf(tile[(c4 + i) * 33 + r]);
    *(v4u16*)&wt[(size_t)(n0 + r) * K + k0 + c4] = uv;
  }
}

// ---------------- concat qkv bias ------------------------------------------
__global__ void bcat_k(const float* bq, const float* bk, const float* bv, float* dst) {
  int i = blockIdx.x * 256 + threadIdx.x;  // 3072
  dst[i] = i < 1024 ? bq[i] : (i < 2048 ? bk[i - 1024] : bv[i - 2048]);
}

// ---------------- mask int32 -> bitmask (bit=1 keep), vectorized -----------
__global__ __launch_bounds__(256)
void mask_k(const int* __restrict__ mask, unsigned* __restrict__ mw) {
  const size_t w = (size_t)blockIdx.x * 256 + threadIdx.x;   // 524288 words
  const int4* p = (const int4*)(mask + w * 32);
  unsigned bits = 0;
  #pragma unroll
  for (int k = 0; k < 8; k++) {
    const int4 v = p[k];
    bits |= (v.x != 0 ? 1u : 0u) << (k * 4 + 0);
    bits |= (v.y != 0 ? 1u : 0u) << (k * 4 + 1);
    bits |= (v.z != 0 ? 1u : 0u) << (k * 4 + 2);
    bits |= (v.w != 0 ? 1u : 0u) << (k * 4 + 3);
  }
  mw[w] = bits;
}

// ---------------- V -> Vt[b][h][dk][s] --------------------------------------
__global__ __launch_bounds__(256)
void vt_k(const u16* __restrict__ qkv, u16* __restrict__ vt) {
  __shared__ __align__(16) u16 tile[64 * 72];
  const int t = threadIdx.x;
  const int bh = blockIdx.y, b = bh >> 4, h = bh & 15;
  const size_t s0 = (size_t)blockIdx.x * 64;
  {
    const int row = t >> 2, c0 = (t & 3) << 4;
    const u16* src = &qkv[((size_t)b * Ss + s0 + row) * 3072 + 2048 + h * 64 + c0];
    *(v8s*)&tile[row * 72 + c0] = *(const v8s*)src;
    *(v8s*)&tile[row * 72 + c0 + 8] = *(const v8s*)(src + 8);
  }
  __syncthreads();
  {
    const int dk = t >> 2, sc0 = (t & 3) << 4;
    u16* dst = &vt[((size_t)bh * 64 + dk) * Ss + s0 + sc0];
    v4u16 a, bvv, cvv, d;
    #pragma unroll
    for (int i = 0; i < 4; i++) a[i] = tile[(sc0 + i) * 72 + dk];
    #pragma unroll
    for (int i = 0; i < 4; i++) bvv[i] = tile[(sc0 + 4 + i) * 72 + dk];
    #pragma unroll
    for (int i = 0; i < 4; i++) cvv[i] = tile[(sc0 + 8 + i) * 72 + dk];
    #pragma unroll
    for (int i = 0; i < 4; i++) d[i] = tile[(sc0 + 12 + i) * 72 + dk];
    *(v4u16*)(dst + 0) = a; *(v4u16*)(dst + 4) = bvv;
    *(v4u16*)(dst + 8) = cvv; *(v4u16*)(dst + 12) = d;
  }
}

// ---------------- GEMM: C = A[M][K](bf16) @ Bt[N][K]^T + bias ---------------
// T3-minimum 2-phase schedule (catalog-verified): STAGE(t+1) into buf[cur^1]
// issued BEFORE ds_read+MFMA of buf[cur]; ONE vmcnt(0)+barrier per K-step at
// iteration END. The whole MFMA phase covers the next tile's HBM latency
// (old structure drained vmcnt immediately after stage = exposed latency).
// 128x128 tile, BK=32, 2 buffers (32 KB), 4 waves, launch_bounds(256,3),
// XCD-swizzled bid. EPI 0: bf16; 1: fp32 res; 2: gelu.
template<int EPI>
__global__ __launch_bounds__(256, 3)
void gemm_bt(const u16* __restrict__ A, const u16* __restrict__ Bt,
             const float* __restrict__ bias, const float* res,
             void* out, int M, int N, int K) {
  __shared__ __align__(16) u16 lA[2][128 * 32];
  __shared__ __align__(16) u16 lB[2][128 * 32];
  const int tid = threadIdx.x;
  const int lane = tid & 63, wid = tid >> 6;
  const int c = lane & 15, g = lane >> 4;
  const int nt = N >> 7;
  const int nwg = gridDim.x;
  const int bid0 = blockIdx.x;
  const int bid = (bid0 & 7) * (nwg >> 3) + (bid0 >> 3);   // XCD swizzle (nwg%8==0)
  const int bm = bid / nt, bn = bid - bm * nt;
  const int row0 = bm << 7, col0 = bn << 7;
  const int wr = (wid >> 1) << 6, wc = (wid & 1) << 6;

  v4f acc[4][4] = {};

  const int arow = tid >> 2, ak = (tid & 3) << 3;
  const u16* gA = A + (size_t)(row0 + arow) * K + ak;
  const u16* gB = Bt + (size_t)(col0 + arow) * K + ak;
  const int ldo = wid * 512;
  const size_t rstep = (size_t)64 * K;
  const int NT = K >> 5;

  auto stage = [&](int t, int buf) {
    const int ks = t << 5;
    gload16(gA + ks, &lA[buf][ldo]);
    gload16(gA + ks + rstep, &lA[buf][ldo + 2048]);
    gload16(gB + ks, &lB[buf][ldo]);
    gload16(gB + ks + rstep, &lB[buf][ldo + 2048]);
  };

  stage(0, 0);
  asm volatile("s_waitcnt vmcnt(0)" ::: "memory");
  __builtin_amdgcn_s_barrier();
  asm volatile("" ::: "memory");

  int cur = 0;
  for (int t = 0; t < NT; t++) {
    if (t + 1 < NT) stage(t + 1, cur ^ 1);    // issue next-tile loads FIRST
    v8s af[4], bfr[4];
    #pragma unroll
    for (int m = 0; m < 4; m++) af[m] = *(const v8s*)&lA[cur][(wr + m * 16 + c) * 32 + g * 8];
    #pragma unroll
    for (int n = 0; n < 4; n++) bfr[n] = *(const v8s*)&lB[cur][(wc + n * 16 + c) * 32 + g * 8];
    #pragma unroll
    for (int m = 0; m < 4; m++)
      #pragma unroll
      for (int n = 0; n < 4; n++)
        acc[m][n] = mfma16(af[m], bfr[n], acc[m][n]);
    if (t + 1 < NT) {
      asm volatile("s_waitcnt vmcnt(0)" ::: "memory");   // t+1 resident
      __builtin_amdgcn_s_barrier();
      asm volatile("" ::: "memory");
      cur ^= 1;
    }
  }

  float bv[4];
  #pragma unroll
  for (int n = 0; n < 4; n++) bv[n] = bias[col0 + wc + n * 16 + c];
  #pragma unroll
  for (int m = 0; m < 4; m++) {
    #pragma unroll
    for (int n = 0; n < 4; n++) {
      #pragma unroll
      for (int j = 0; j < 4; j++) {
        const int r = row0 + wr + m * 16 + g * 4 + j;
        const int cc = col0 + wc + n * 16 + c;
        const size_t idx = (size_t)r * N + cc;
        const float v = acc[m][n][j] + bv[n];
        if constexpr (EPI == 0) ((u16*)out)[idx] = f2bf(v);
        else if constexpr (EPI == 1) ((float*)out)[idx] = res[idx] + v;
        else ((u16*)out)[idx] = f2bf(gelu_f(v));
      }
    }
  }
}

// ---------------- flash attention (swapped QK^T, in-register P) -------------
// r18 version (best measured: 121us): gload_lds K/V staging with XOR-swizzle
// (0 bank conflicts), no-max softmax with pre-folded mask + Schraudolph exp2,
// setprio around MFMA clusters, VALU xor-32 reduce, PV inside m-loop.
__global__ __launch_bounds__(256, 4)
void attn_k(const u16* __restrict__ qkv, const u16* __restrict__ vt,
            const unsigned* __restrict__ mw, u16* __restrict__ ctx) {
  __shared__ __align__(16) u16 lK[128 * 64];
  __shared__ __align__(16) u16 lV[64 * 128];

  const int tid = threadIdx.x, lane = tid & 63, wid = tid >> 6;
  const int c = lane & 15, g = lane >> 4;
  const bool b4 = (lane & 16) != 0;
  const int bid = blockIdx.x;
  const int swz = (bid & 7) * 128 + (bid >> 3);   // 1024 blocks, 8 XCDs
  const int bh = swz >> 4, qb = swz & 15;
  const int b = bh >> 4, h = bh & 15;
  const int qw = (qb << 7) + wid * 32;

  v8s qs[2][2];
  #pragma unroll
  for (int m = 0; m < 2; m++)
    #pragma unroll
    for (int ks = 0; ks < 2; ks++) {
      const v8s q = *(const v8s*)&qkv[((size_t)b * Ss + qw + m * 16 + c) * 3072 + h * 64 + ks * 32 + g * 8];
      v4u w;
      #pragma unroll
      for (int p = 0; p < 4; p++) {
        const float a = __builtin_bit_cast(float, (unsigned)((u16)q[2 * p]) << 16) * 0.18033688f;
        const float e = __builtin_bit_cast(float, (unsigned)((u16)q[2 * p + 1]) << 16) * 0.18033688f;
        w[p] = cvtpk(a, e);
      }
      qs[m][ks] = __builtin_bit_cast(v8s, w);
    }

  v4f o[2][4] = {};
  float ls[2] = {0.f, 0.f};

  const unsigned* mrow0 = mw + ((size_t)b * Ss + qw + c) * 64;

  const int skey = tid >> 3;
  const int kchunk = (((tid & 7) ^ ((tid >> 3) & 7)) << 3);
  const int vdk = tid >> 4;
  const int vchunk = (((tid & 15) ^ ((tid >> 4) & 15)) << 3);
  const u16* gK = &qkv[((size_t)b * Ss + skey) * 3072 + 1024 + h * 64 + kchunk];
  const u16* gV = &vt[((size_t)bh * 64 + vdk) * Ss + vchunk];
  u16* const dK = &lK[(wid * 8) * 64];
  u16* const dV = &lV[(wid * 4) * 128];

  for (int kt = 0; kt < 16; kt++) {
    __syncthreads();
    #pragma unroll
    for (int i = 0; i < 4; i++) {
      gload16(gK + ((size_t)kt * 128 + i * 32) * 3072, dK + i * (32 * 64));
      gload16(gV + (size_t)(i * 16) * Ss + kt * 128, dV + i * (16 * 128));
    }
    __syncthreads();

    #pragma unroll
    for (int m = 0; m < 2; m++) {
      v4f sc[8] = {};
      __builtin_amdgcn_s_setprio(1);
      #pragma unroll
      for (int f = 0; f < 8; f++) {
        const v8s k0 = *(const v8s*)&lK[(f * 16 + c) * 64 + ((g ^ (c & 7)) << 3)];
        const v8s k1 = *(const v8s*)&lK[(f * 16 + c) * 64 + (((g + 4) ^ (c & 7)) << 3)];
        sc[f] = mfma16(k0, qs[m][0], sc[f]);
        sc[f] = mfma16(k1, qs[m][1], sc[f]);
      }
      __builtin_amdgcn_s_setprio(0);
      const uint4 mv = *(const uint4*)(mrow0 + (size_t)m * 16 * 64 + kt * 4);
      const unsigned mvw[4] = {mv.x, mv.y, mv.z, mv.w};
      float rs = 0.f;
      #pragma unroll
      for (int f = 0; f < 8; f++) {
        const unsigned bits = mvw[f >> 1] >> (((f & 1) << 4) + (g << 2));
        #pragma unroll
        for (int j = 0; j < 4; j++) {
          const float sm = ((bits >> j) & 1u) ? sc[f][j] : -126.0f;
          const float p = fexp2_raw(sm);
          sc[f][j] = p;
          rs += p;
        }
      }
      rs += __shfl_xor(rs, 16);
      {  // xor-32 butterfly on the VALU via permlane32_swap
        unsigned ru = __builtin_bit_cast(unsigned, rs), rv = ru;
        asm("v_permlane32_swap_b32 %0, %1" : "+v"(ru), "+v"(rv));
        rs = __builtin_bit_cast(float, ru) + __builtin_bit_cast(float, rv);
      }
      ls[m] += rs;
      unsigned p0[8], p1[8];
      #pragma unroll
      for (int f = 0; f < 8; f++) {
        p0[f] = cvtpk(sc[f][0], sc[f][1]);
        p1[f] = cvtpk(sc[f][2], sc[f][3]);
      }
      __builtin_amdgcn_s_setprio(1);
      #pragma unroll
      for (int kk = 0; kk < 4; kk++) {
        unsigned X0 = p0[2 * kk],     X1 = p1[2 * kk];
        unsigned Y0 = p0[2 * kk + 1], Y1 = p1[2 * kk + 1];
        asm("v_permlane32_swap_b32 %0, %1" : "+v"(Y0), "+v"(X0));
        asm("v_permlane32_swap_b32 %0, %1" : "+v"(Y1), "+v"(X1));
        const unsigned A0 = b4 ? (unsigned)__shfl_xor((int)Y0, 16) : X0;
        const unsigned A1 = b4 ? (unsigned)__shfl_xor((int)Y1, 16) : X1;
        const unsigned B0 = b4 ? Y0 : (unsigned)__shfl_xor((int)X0, 16);
        const unsigned B1 = b4 ? Y1 : (unsigned)__shfl_xor((int)X1, 16);
        uint4 t4; t4.x = A0; t4.y = A1; t4.z = B0; t4.w = B1;
        const v8s a8 = __builtin_bit_cast(v8s, t4);
        #pragma unroll
        for (int n = 0; n < 4; n++) {
          const v8s vb = *(const v8s*)&lV[(n * 16 + c) * 128 + (((kk * 4 + g) ^ c) << 3)];
          o[m][n] = mfma16(a8, vb, o[m][n]);
        }
      }
      __builtin_amdgcn_s_setprio(0);
    }
  }

  #pragma unroll
  for (int m = 0; m < 2; m++) {
    #pragma unroll
    for (int j = 0; j < 4; j++) {
      const float lsj = __shfl(ls[m], (g << 2) + j);
      const float inv = lsj > 0.f ? 1.0f / lsj : 0.f;
      const size_t row = (size_t)b * Ss + qw + m * 16 + (g << 2) + j;
      #pragma unroll
      for (int n = 0; n < 4; n++)
        ctx[row * Dd + h * 64 + n * 16 + c] = f2bf(o[m][n][j] * inv);
    }
  }
}

// ---------------- launch -----------------------------------------------------
extern "C" void kernel_launch(void* const* d_in, const int* in_sizes, int n_in,
                              void* d_out, int out_size, void* d_ws, size_t ws_size,
                              hipStream_t stream) {
  const float* x    = (const float*)d_in[0];
  const int*   mask = (const int*)d_in[1];
  const float* ln1a = (const float*)d_in[2];
  const float* ln1b = (const float*)d_in[3];
  const float* Wq   = (const float*)d_in[4];
  const float* bq   = (const float*)d_in[5];
  const float* Wk   = (const float*)d_in[6];
  const float* bk   = (const float*)d_in[7];
  const float* Wv   = (const float*)d_in[8];
  const float* bv   = (const float*)d_in[9];
  const float* Wo   = (const float*)d_in[10];
  const float* bo   = (const float*)d_in[11];
  const float* ln2a = (const float*)d_in[12];
  const float* ln2b = (const float*)d_in[13];
  const float* W1   = (const float*)d_in[14];
  const float* b1   = (const float*)d_in[15];
  const float* W2   = (const float*)d_in[16];
  const float* b2   = (const float*)d_in[17];
  float* out = (float*)d_out;

  // workspace layout (~139 MB total)
  char* ws = (char*)d_ws;
  u16* wqkvT    = (u16*)(ws);                   // [3072][1024] bf16
  u16* woT      = (u16*)(ws + 6291456);         // [1024][1024]
  u16* w1T      = (u16*)(ws + 8388608);         // [4096][1024]
  u16* w2T      = (u16*)(ws + 16777216);        // [1024][4096]
  float* bqkv   = (float*)(ws + 25165824);      // [3072]
  unsigned* mw  = (unsigned*)(ws + 25178112);   // [B][S][S/32] bits
  u16* xb       = (u16*)(ws + 27275264);        // [8192][1024] (xb1, later xb2)
  u16* qkv      = (u16*)(ws + 44052480);        // 64MB slot: qkv, later h1
  u16* h1       = qkv;                          // [8192][4096]
  u16* vt       = (u16*)(ws + 111161344);       // [B][H][64][S]
  u16* ctx      = (u16*)(ws + 127938560);       // [8192][1024]

  wt_k<<<dim3(32, 32),  256, 0, stream>>>(Wq, wqkvT,           1024, 1024);
  wt_k<<<dim3(32, 32),  256, 0, stream>>>(Wk, wqkvT + 1048576, 1024, 1024);
  wt_k<<<dim3(32, 32),  256, 0, stream>>>(Wv, wqkvT + 2097152, 1024, 1024);
  wt_k<<<dim3(32, 32),  256, 0, stream>>>(Wo, woT,             1024, 1024);
  wt_k<<<dim3(32, 128), 256, 0, stream>>>(W1, w1T,             1024, 4096);
  wt_k<<<dim3(128, 32), 256, 0, stream>>>(W2, w2T,             4096, 1024);
  bcat_k<<<12, 256, 0, stream>>>(bq, bk, bv, bqkv);
  mask_k<<<2048, 256, 0, stream>>>(mask, mw);
  ln_k<<<8192, 256, 0, stream>>>(x, ln1a, ln1b, xb);

  gemm_bt<0><<<64 * 24, 256, 0, stream>>>(xb, wqkvT, bqkv, nullptr, qkv, 8192, 3072, 1024);
  vt_k<<<dim3(32, 64), 256, 0, stream>>>(qkv, vt);
  attn_k<<<1024, 256, 0, stream>>>(qkv, vt, mw, ctx);
  gemm_bt<1><<<64 * 8, 256, 0, stream>>>(ctx, woT, bo, x, out, 8192, 1024, 1024);
  ln_k<<<8192, 256, 0, stream>>>(out, ln2a, ln2b, xb);
  gemm_bt<2><<<64 * 32, 256, 0, stream>>>(xb, w1T, b1, nullptr, h1, 8192, 4096, 1024);
  gemm_bt<1><<<64 * 8, 256, 0, stream>>>(h1, w2T, b2, out, out, 8192, 1024, 4096);
}

// Round 20
// 466.181 us; speedup vs baseline: 1.0518x; 1.0518x over previous
//
#include <hip/hip_runtime.h>

#define Bb 4
#define Ss 2048
#define Dd 1024
#define Hh 16
#define DFF 4096

typedef unsigned short u16;
typedef __attribute__((ext_vector_type(8))) short v8s;
typedef __attribute__((ext_vector_type(4))) float v4f;
typedef __attribute__((ext_vector_type(4))) unsigned short v4u16;
typedef __attribute__((ext_vector_type(4))) unsigned v4u;

__device__ __forceinline__ u16 f2bf(float f) {
  unsigned u = __builtin_bit_cast(unsigned, f);
  return (u16)((u + 0x7fffu + ((u >> 16) & 1u)) >> 16);   // RNE
}

__device__ __forceinline__ unsigned cvtpk(float a, float b) {
  unsigned r;
  asm("v_cvt_pk_bf16_f32 %0, %1, %2" : "=v"(r) : "v"(a), "v"(b));
  return r;
}

__device__ __forceinline__ void gload16(const void* g, void* l) {
  __builtin_amdgcn_global_load_lds((const __attribute__((address_space(1))) unsigned*)g,
                                   (__attribute__((address_space(3))) unsigned*)l, 16, 0, 0);
}

__device__ __forceinline__ v4f mfma16(v8s a, v8s b, v4f c) {
  return __builtin_amdgcn_mfma_f32_16x16x32_bf16(a, b, c, 0, 0, 0);
}

// Schraudolph fast exp2 (mask pre-folded by caller; scores |s|<~30).
__device__ __forceinline__ float fexp2_raw(float s) {
  const int i = (int)__builtin_fmaf(s, 8388608.0f, 1064998378.0f);
  return __builtin_bit_cast(float, i);
}

__device__ __forceinline__ float gelu_f(float x) {
  float y = 0.7978845608028654f * (x + 0.044715f * x * x * x);
  y = fminf(fmaxf(y, -15.f), 15.f);
  float t = 1.0f - 2.0f / (__expf(2.0f * y) + 1.0f);
  return 0.5f * x * (1.0f + t);
}

// ---------------- LayerNorm (ddof=1, eps on std), fp32 in -> bf16 out -------
__global__ __launch_bounds__(256)
void ln_k(const float* __restrict__ x, const float* __restrict__ ga,
          const float* __restrict__ gb, u16* __restrict__ out) {
  const int row = blockIdx.x, tid = threadIdx.x;
  const float4 v = ((const float4*)(x + (size_t)row * 1024))[tid];
  float s = v.x + v.y + v.z + v.w;
  float q = v.x * v.x + v.y * v.y + v.z * v.z + v.w * v.w;
  #pragma unroll
  for (int o = 1; o < 64; o <<= 1) { s += __shfl_xor(s, o); q += __shfl_xor(q, o); }
  __shared__ float red[8];
  if ((tid & 63) == 0) { red[tid >> 6] = s; red[4 + (tid >> 6)] = q; }
  __syncthreads();
  s = red[0] + red[1] + red[2] + red[3];
  q = red[4] + red[5] + red[6] + red[7];
  const float mean = s * (1.0f / 1024.0f);
  const float var = fmaxf((q - 1024.0f * mean * mean) * (1.0f / 1023.0f), 0.0f);
  const float inv = 1.0f / (sqrtf(var) + 1e-6f);
  const int c0 = tid * 4;
  u16* o4 = out + (size_t)row * 1024 + c0;
  const float vv[4] = {v.x, v.y, v.z, v.w};
  #pragma unroll
  for (int i = 0; i < 4; i++)
    o4[i] = f2bf(ga[c0 + i] * (vv[i] - mean) * inv + gb[c0 + i]);
}

// ---------------- weight transpose: W[K][N] fp32 -> Wt[N][K] bf16 -----------
__global__ __launch_bounds__(256)
void wt_k(const float* __restrict__ w, u16* __restrict__ wt, int K, int N) {
  __shared__ float tile[32 * 33];
  const int t = threadIdx.x;
  const int k0 = blockIdx.x << 5, n0 = blockIdx.y << 5;
  {
    const int r = t >> 3, c4 = (t & 7) << 2;
    const float4 v = *(const float4*)&w[(size_t)(k0 + r) * N + n0 + c4];
    tile[r * 33 + c4 + 0] = v.x; tile[r * 33 + c4 + 1] = v.y;
    tile[r * 33 + c4 + 2] = v.z; tile[r * 33 + c4 + 3] = v.w;
  }
  __syncthreads();
  {
    const int r = t >> 3, c4 = (t & 7) << 2;  // r: n-offset, c4: k-offset
    v4u16 uv;
    #pragma unroll
    for (int i = 0; i < 4; i++) uv[i] = f2bf(tile[(c4 + i) * 33 + r]);
    *(v4u16*)&wt[(size_t)(n0 + r) * K + k0 + c4] = uv;
  }
}

// ---------------- concat qkv bias ------------------------------------------
__global__ void bcat_k(const float* bq, const float* bk, const float* bv, float* dst) {
  int i = blockIdx.x * 256 + threadIdx.x;  // 3072
  dst[i] = i < 1024 ? bq[i] : (i < 2048 ? bk[i - 1024] : bv[i - 2048]);
}

// ---------------- mask int32 -> bitmask (bit=1 keep), vectorized -----------
__global__ __launch_bounds__(256)
void mask_k(const int* __restrict__ mask, unsigned* __restrict__ mw) {
  const size_t w = (size_t)blockIdx.x * 256 + threadIdx.x;   // 524288 words
  const int4* p = (const int4*)(mask + w * 32);
  unsigned bits = 0;
  #pragma unroll
  for (int k = 0; k < 8; k++) {
    const int4 v = p[k];
    bits |= (v.x != 0 ? 1u : 0u) << (k * 4 + 0);
    bits |= (v.y != 0 ? 1u : 0u) << (k * 4 + 1);
    bits |= (v.z != 0 ? 1u : 0u) << (k * 4 + 2);
    bits |= (v.w != 0 ? 1u : 0u) << (k * 4 + 3);
  }
  mw[w] = bits;
}

// ---------------- V -> Vt[b][h][dk][s] --------------------------------------
__global__ __launch_bounds__(256)
void vt_k(const u16* __restrict__ qkv, u16* __restrict__ vt) {
  __shared__ __align__(16) u16 tile[64 * 72];
  const int t = threadIdx.x;
  const int bh = blockIdx.y, b = bh >> 4, h = bh & 15;
  const size_t s0 = (size_t)blockIdx.x * 64;
  {
    const int row = t >> 2, c0 = (t & 3) << 4;
    const u16* src = &qkv[((size_t)b * Ss + s0 + row) * 3072 + 2048 + h * 64 + c0];
    *(v8s*)&tile[row * 72 + c0] = *(const v8s*)src;
    *(v8s*)&tile[row * 72 + c0 + 8] = *(const v8s*)(src + 8);
  }
  __syncthreads();
  {
    const int dk = t >> 2, sc0 = (t & 3) << 4;
    u16* dst = &vt[((size_t)bh * 64 + dk) * Ss + s0 + sc0];
    v4u16 a, bvv, cvv, d;
    #pragma unroll
    for (int i = 0; i < 4; i++) a[i] = tile[(sc0 + i) * 72 + dk];
    #pragma unroll
    for (int i = 0; i < 4; i++) bvv[i] = tile[(sc0 + 4 + i) * 72 + dk];
    #pragma unroll
    for (int i = 0; i < 4; i++) cvv[i] = tile[(sc0 + 8 + i) * 72 + dk];
    #pragma unroll
    for (int i = 0; i < 4; i++) d[i] = tile[(sc0 + 12 + i) * 72 + dk];
    *(v4u16*)(dst + 0) = a; *(v4u16*)(dst + 4) = bvv;
    *(v4u16*)(dst + 8) = cvv; *(v4u16*)(dst + 12) = d;
  }
}

// ---------------- GEMM: C = A[M][K](bf16) @ Bt[N][K]^T + bias ---------------
// r18 version (best measured): 128x128 tile, 4 waves, XCD-swizzled bid,
// BK=64 as two 32-col panels in separate [128][32] LDS buffers (one barrier
// pair per 64 K, 32 MFMA per barrier), launch_bounds(256,3) -> 3 blocks/CU.
template<int EPI>
__global__ __launch_bounds__(256, 3)
void gemm_bt(const u16* __restrict__ A, const u16* __restrict__ Bt,
             const float* __restrict__ bias, const float* res,
             void* out, int M, int N, int K) {
  __shared__ __align__(16) u16 lA[2][128 * 32];
  __shared__ __align__(16) u16 lB[2][128 * 32];
  const int tid = threadIdx.x;
  const int lane = tid & 63, wid = tid >> 6;
  const int c = lane & 15, g = lane >> 4;
  const int nt = N >> 7;
  const int nwg = gridDim.x;
  const int bid0 = blockIdx.x;
  const int bid = (bid0 & 7) * (nwg >> 3) + (bid0 >> 3);   // XCD swizzle (nwg%8==0)
  const int bm = bid / nt, bn = bid - bm * nt;
  const int row0 = bm << 7, col0 = bn << 7;
  const int wr = (wid >> 1) << 6, wc = (wid & 1) << 6;

  v4f acc[4][4] = {};

  const int arow = tid >> 2, ak = (tid & 3) << 3;
  const u16* gA = A + (size_t)(row0 + arow) * K + ak;
  const u16* gB = Bt + (size_t)(col0 + arow) * K + ak;
  const int ldo = wid * 512;
  const size_t rstep = (size_t)64 * K;

  for (int kt = 0; kt < K; kt += 64) {
    __syncthreads();
    #pragma unroll
    for (int s = 0; s < 2; s++) {
      const int ks = kt + s * 32;
      gload16(gA + ks, &lA[s][ldo]);
      gload16(gA + ks + rstep, &lA[s][ldo + 2048]);
      gload16(gB + ks, &lB[s][ldo]);
      gload16(gB + ks + rstep, &lB[s][ldo + 2048]);
    }
    __syncthreads();
    #pragma unroll
    for (int s = 0; s < 2; s++) {
      v8s af[4], bfr[4];
      #pragma unroll
      for (int m = 0; m < 4; m++) af[m] = *(const v8s*)&lA[s][(wr + m * 16 + c) * 32 + g * 8];
      #pragma unroll
      for (int n = 0; n < 4; n++) bfr[n] = *(const v8s*)&lB[s][(wc + n * 16 + c) * 32 + g * 8];
      #pragma unroll
      for (int m = 0; m < 4; m++)
        #pragma unroll
        for (int n = 0; n < 4; n++)
          acc[m][n] = mfma16(af[m], bfr[n], acc[m][n]);
    }
  }

  float bv[4];
  #pragma unroll
  for (int n = 0; n < 4; n++) bv[n] = bias[col0 + wc + n * 16 + c];
  #pragma unroll
  for (int m = 0; m < 4; m++) {
    #pragma unroll
    for (int n = 0; n < 4; n++) {
      #pragma unroll
      for (int j = 0; j < 4; j++) {
        const int r = row0 + wr + m * 16 + g * 4 + j;
        const int cc = col0 + wc + n * 16 + c;
        const size_t idx = (size_t)r * N + cc;
        const float v = acc[m][n][j] + bv[n];
        if constexpr (EPI == 0) ((u16*)out)[idx] = f2bf(v);
        else if constexpr (EPI == 1) ((float*)out)[idx] = res[idx] + v;
        else ((u16*)out)[idx] = f2bf(gelu_f(v));
      }
    }
  }
}

// ---------------- flash attention (swapped QK^T, in-register P) -------------
// r18 version (best measured: 121us): gload_lds K/V staging with XOR-swizzle
// (0 bank conflicts), no-max softmax with pre-folded mask + Schraudolph exp2,
// setprio around MFMA clusters, VALU xor-32 reduce, PV inside m-loop.
__global__ __launch_bounds__(256, 4)
void attn_k(const u16* __restrict__ qkv, const u16* __restrict__ vt,
            const unsigned* __restrict__ mw, u16* __restrict__ ctx) {
  __shared__ __align__(16) u16 lK[128 * 64];
  __shared__ __align__(16) u16 lV[64 * 128];

  const int tid = threadIdx.x, lane = tid & 63, wid = tid >> 6;
  const int c = lane & 15, g = lane >> 4;
  const bool b4 = (lane & 16) != 0;
  const int bid = blockIdx.x;
  const int swz = (bid & 7) * 128 + (bid >> 3);   // 1024 blocks, 8 XCDs
  const int bh = swz >> 4, qb = swz & 15;
  const int b = bh >> 4, h = bh & 15;
  const int qw = (qb << 7) + wid * 32;

  v8s qs[2][2];
  #pragma unroll
  for (int m = 0; m < 2; m++)
    #pragma unroll
    for (int ks = 0; ks < 2; ks++) {
      const v8s q = *(const v8s*)&qkv[((size_t)b * Ss + qw + m * 16 + c) * 3072 + h * 64 + ks * 32 + g * 8];
      v4u w;
      #pragma unroll
      for (int p = 0; p < 4; p++) {
        const float a = __builtin_bit_cast(float, (unsigned)((u16)q[2 * p]) << 16) * 0.18033688f;
        const float e = __builtin_bit_cast(float, (unsigned)((u16)q[2 * p + 1]) << 16) * 0.18033688f;
        w[p] = cvtpk(a, e);
      }
      qs[m][ks] = __builtin_bit_cast(v8s, w);
    }

  v4f o[2][4] = {};
  float ls[2] = {0.f, 0.f};

  const unsigned* mrow0 = mw + ((size_t)b * Ss + qw + c) * 64;

  const int skey = tid >> 3;
  const int kchunk = (((tid & 7) ^ ((tid >> 3) & 7)) << 3);
  const int vdk = tid >> 4;
  const int vchunk = (((tid & 15) ^ ((tid >> 4) & 15)) << 3);
  const u16* gK = &qkv[((size_t)b * Ss + skey) * 3072 + 1024 + h * 64 + kchunk];
  const u16* gV = &vt[((size_t)bh * 64 + vdk) * Ss + vchunk];
  u16* const dK = &lK[(wid * 8) * 64];
  u16* const dV = &lV[(wid * 4) * 128];

  for (int kt = 0; kt < 16; kt++) {
    __syncthreads();
    #pragma unroll
    for (int i = 0; i < 4; i++) {
      gload16(gK + ((size_t)kt * 128 + i * 32) * 3072, dK + i * (32 * 64));
      gload16(gV + (size_t)(i * 16) * Ss + kt * 128, dV + i * (16 * 128));
    }
    __syncthreads();

    #pragma unroll
    for (int m = 0; m < 2; m++) {
      v4f sc[8] = {};
      __builtin_amdgcn_s_setprio(1);
      #pragma unroll
      for (int f = 0; f < 8; f++) {
        const v8s k0 = *(const v8s*)&lK[(f * 16 + c) * 64 + ((g ^ (c & 7)) << 3)];
        const v8s k1 = *(const v8s*)&lK[(f * 16 + c) * 64 + (((g + 4) ^ (c & 7)) << 3)];
        sc[f] = mfma16(k0, qs[m][0], sc[f]);
        sc[f] = mfma16(k1, qs[m][1], sc[f]);
      }
      __builtin_amdgcn_s_setprio(0);
      const uint4 mv = *(const uint4*)(mrow0 + (size_t)m * 16 * 64 + kt * 4);
      const unsigned mvw[4] = {mv.x, mv.y, mv.z, mv.w};
      float rs = 0.f;
      #pragma unroll
      for (int f = 0; f < 8; f++) {
        const unsigned bits = mvw[f >> 1] >> (((f & 1) << 4) + (g << 2));
        #pragma unroll
        for (int j = 0; j < 4; j++) {
          const float sm = ((bits >> j) & 1u) ? sc[f][j] : -126.0f;
          const float p = fexp2_raw(sm);
          sc[f][j] = p;
          rs += p;
        }
      }
      rs += __shfl_xor(rs, 16);
      {  // xor-32 butterfly on the VALU via permlane32_swap
        unsigned ru = __builtin_bit_cast(unsigned, rs), rv = ru;
        asm("v_permlane32_swap_b32 %0, %1" : "+v"(ru), "+v"(rv));
        rs = __builtin_bit_cast(float, ru) + __builtin_bit_cast(float, rv);
      }
      ls[m] += rs;
      unsigned p0[8], p1[8];
      #pragma unroll
      for (int f = 0; f < 8; f++) {
        p0[f] = cvtpk(sc[f][0], sc[f][1]);
        p1[f] = cvtpk(sc[f][2], sc[f][3]);
      }
      __builtin_amdgcn_s_setprio(1);
      #pragma unroll
      for (int kk = 0; kk < 4; kk++) {
        unsigned X0 = p0[2 * kk],     X1 = p1[2 * kk];
        unsigned Y0 = p0[2 * kk + 1], Y1 = p1[2 * kk + 1];
        asm("v_permlane32_swap_b32 %0, %1" : "+v"(Y0), "+v"(X0));
        asm("v_permlane32_swap_b32 %0, %1" : "+v"(Y1), "+v"(X1));
        const unsigned A0 = b4 ? (unsigned)__shfl_xor((int)Y0, 16) : X0;
        const unsigned A1 = b4 ? (unsigned)__shfl_xor((int)Y1, 16) : X1;
        const unsigned B0 = b4 ? Y0 : (unsigned)__shfl_xor((int)X0, 16);
        const unsigned B1 = b4 ? Y1 : (unsigned)__shfl_xor((int)X1, 16);
        uint4 t4; t4.x = A0; t4.y = A1; t4.z = B0; t4.w = B1;
        const v8s a8 = __builtin_bit_cast(v8s, t4);
        #pragma unroll
        for (int n = 0; n < 4; n++) {
          const v8s vb = *(const v8s*)&lV[(n * 16 + c) * 128 + (((kk * 4 + g) ^ c) << 3)];
          o[m][n] = mfma16(a8, vb, o[m][n]);
        }
      }
      __builtin_amdgcn_s_setprio(0);
    }
  }

  #pragma unroll
  for (int m = 0; m < 2; m++) {
    #pragma unroll
    for (int j = 0; j < 4; j++) {
      const float lsj = __shfl(ls[m], (g << 2) + j);
      const float inv = lsj > 0.f ? 1.0f / lsj : 0.f;
      const size_t row = (size_t)b * Ss + qw + m * 16 + (g << 2) + j;
      #pragma unroll
      for (int n = 0; n < 4; n++)
        ctx[row * Dd + h * 64 + n * 16 + c] = f2bf(o[m][n][j] * inv);
    }
  }
}

// ---------------- launch -----------------------------------------------------
extern "C" void kernel_launch(void* const* d_in, const int* in_sizes, int n_in,
                              void* d_out, int out_size, void* d_ws, size_t ws_size,
                              hipStream_t stream) {
  const float* x    = (const float*)d_in[0];
  const int*   mask = (const int*)d_in[1];
  const float* ln1a = (const float*)d_in[2];
  const float* ln1b = (const float*)d_in[3];
  const float* Wq   = (const float*)d_in[4];
  const float* bq   = (const float*)d_in[5];
  const float* Wk   = (const float*)d_in[6];
  const float* bk   = (const float*)d_in[7];
  const float* Wv   = (const float*)d_in[8];
  const float* bv   = (const float*)d_in[9];
  const float* Wo   = (const float*)d_in[10];
  const float* bo   = (const float*)d_in[11];
  const float* ln2a = (const float*)d_in[12];
  const float* ln2b = (const float*)d_in[13];
  const float* W1   = (const float*)d_in[14];
  const float* b1   = (const float*)d_in[15];
  const float* W2   = (const float*)d_in[16];
  const float* b2   = (const float*)d_in[17];
  float* out = (float*)d_out;

  // workspace layout (~139 MB total)
  char* ws = (char*)d_ws;
  u16* wqkvT    = (u16*)(ws);                   // [3072][1024] bf16
  u16* woT      = (u16*)(ws + 6291456);         // [1024][1024]
  u16* w1T      = (u16*)(ws + 8388608);         // [4096][1024]
  u16* w2T      = (u16*)(ws + 16777216);        // [1024][4096]
  float* bqkv   = (float*)(ws + 25165824);      // [3072]
  unsigned* mw  = (unsigned*)(ws + 25178112);   // [B][S][S/32] bits
  u16* xb       = (u16*)(ws + 27275264);        // [8192][1024] (xb1, later xb2)
  u16* qkv      = (u16*)(ws + 44052480);        // 64MB slot: qkv, later h1
  u16* h1       = qkv;                          // [8192][4096]
  u16* vt       = (u16*)(ws + 111161344);       // [B][H][64][S]
  u16* ctx      = (u16*)(ws + 127938560);       // [8192][1024]

  wt_k<<<dim3(32, 32),  256, 0, stream>>>(Wq, wqkvT,           1024, 1024);
  wt_k<<<dim3(32, 32),  256, 0, stream>>>(Wk, wqkvT + 1048576, 1024, 1024);
  wt_k<<<dim3(32, 32),  256, 0, stream>>>(Wv, wqkvT + 2097152, 1024, 1024);
  wt_k<<<dim3(32, 32),  256, 0, stream>>>(Wo, woT,             1024, 1024);
  wt_k<<<dim3(32, 128), 256, 0, stream>>>(W1, w1T,             1024, 4096);
  wt_k<<<dim3(128, 32), 256, 0, stream>>>(W2, w2T,             4096, 1024);
  bcat_k<<<12, 256, 0, stream>>>(bq, bk, bv, bqkv);
  mask_k<<<2048, 256, 0, stream>>>(mask, mw);
  ln_k<<<8192, 256, 0, stream>>>(x, ln1a, ln1b, xb);

  gemm_bt<0><<<64 * 24, 256, 0, stream>>>(xb, wqkvT, bqkv, nullptr, qkv, 8192, 3072, 1024);
  vt_k<<<dim3(32, 64), 256, 0, stream>>>(qkv, vt);
  attn_k<<<1024, 256, 0, stream>>>(qkv, vt, mw, ctx);
  gemm_bt<1><<<64 * 8, 256, 0, stream>>>(ctx, woT, bo, x, out, 8192, 1024, 1024);
  ln_k<<<8192, 256, 0, stream>>>(out, ln2a, ln2b, xb);
  gemm_bt<2><<<64 * 32, 256, 0, stream>>>(xb, w1T, b1, nullptr, h1, 8192, 4096, 1024);
  gemm_bt<1><<<64 * 8, 256, 0, stream>>>(h1, w2T, b2, out, out, 8192, 1024, 4096);
}